// Round 9
// baseline (396.486 us; speedup 1.0000x reference)
//
#include <hip/hip_runtime.h>
#include <math.h>

#define NB   4
#define CCH  512
#define LL   4096
#define GRP  32
#define CPG  16
#define CL   (CCH*LL)
#define EPSV 1e-5f
#define QSTR 1024   // QK fused row stride

typedef __bf16 bf16x8 __attribute__((ext_vector_type(8)));
typedef float  f32x4  __attribute__((ext_vector_type(4)));

#define GLOAD_LDS16(g, l) __builtin_amdgcn_global_load_lds( \
    (const __attribute__((address_space(1))) void*)(g),     \
    (__attribute__((address_space(3))) void*)(l), 16, 0, 0)

// ---------------------------------------------------------------------------
// Corrected XOR-swizzle (verified r6: conflicts 2.5e7 -> 6.3e6).
// ---------------------------------------------------------------------------
__device__ __forceinline__ int swz_slot(int row, int q) {
    return 4 * row + (q ^ ((row >> 1) & 3));
}
__device__ __forceinline__ void swz_src(int l, int& jj, int& cc) {
    jj = l >> 2;
    cc = (l & 3) ^ ((l >> 3) & 3);
}

#define DPPF(x, ctrl) __builtin_bit_cast(float, \
    __builtin_amdgcn_update_dpp(0, __builtin_bit_cast(int, (x)), (ctrl), 0xf, 0xf, false))
__device__ __forceinline__ float red_sum16(float x) {
    x += DPPF(x, 0xB1); x += DPPF(x, 0x4E);
    x += DPPF(x, 0x124); x += DPPF(x, 0x128);
    return x;
}

// ---------------------------------------------------------------------------
// GroupNorm pass 1: per (n,g) mean/rstd.
// ---------------------------------------------------------------------------
__global__ __launch_bounds__(1024) void gn_stats(const float* __restrict__ x,
                                                 float* __restrict__ stats) {
    int n = blockIdx.x >> 5, g = blockIdx.x & 31;
    size_t base = ((size_t)n * CCH + (size_t)g * CPG) * LL;
    const float4* xp = (const float4*)(x + base);
    const int NV = CPG * LL / 4;
    int tid = threadIdx.x;
    float s1 = 0.f, s2 = 0.f;
    for (int i = tid; i < NV; i += 1024) {
        float4 v = xp[i];
        s1 += v.x + v.y + v.z + v.w;
        s2 += v.x*v.x + v.y*v.y + v.z*v.z + v.w*v.w;
    }
    __shared__ float red[32];
    for (int o = 32; o; o >>= 1) { s1 += __shfl_down(s1, o); s2 += __shfl_down(s2, o); }
    int lane = tid & 63, w = tid >> 6;
    if (!lane) { red[w] = s1; red[16 + w] = s2; }
    __syncthreads();
    if (tid == 0) {
        float a = 0.f, b = 0.f;
        for (int i = 0; i < 16; ++i) { a += red[i]; b += red[16 + i]; }
        const float inv_n = 1.f / (float)(CPG * LL);
        float mean = a * inv_n;
        float var  = b * inv_n - mean * mean;
        stats[blockIdx.x * 2]     = mean;
        stats[blockIdx.x * 2 + 1] = rsqrtf(var + EPSV);
    }
}

// ---------------------------------------------------------------------------
// GroupNorm pass 2 + transpose: x [C,L] fp32 -> Ht [L,C] bf16.
// v14: vectorized store — each thread packs 8 fp32 from LDS into bf16x8 and
// issues one 16B store (8-lane groups contiguous 128B). Was scalar 2B/lane.
// ---------------------------------------------------------------------------
__global__ __launch_bounds__(256) void gn_norm_t(const float* __restrict__ x,
    const float* __restrict__ gamma, const float* __restrict__ beta,
    const float* __restrict__ stats, __bf16* __restrict__ Ht) {
    __shared__ float T[64][65];
    int n = blockIdx.z, c0 = blockIdx.y * 64, l0 = blockIdx.x * 64;
    int tid = threadIdx.x;
    int lx = tid & 63, py = tid >> 6;
    const float* xb = x + (size_t)n * CL;
#pragma unroll
    for (int p = 0; p < 16; ++p) {
        int cl = p * 4 + py;
        int c = c0 + cl;
        int g = c >> 4;
        float mean = stats[(n * GRP + g) * 2];
        float rstd = stats[(n * GRP + g) * 2 + 1];
        float sc = gamma[c] * rstd, bi = beta[c] - mean * sc;
        float v = xb[(size_t)c * LL + l0 + lx];
        T[lx][cl] = v * sc + bi;
    }
    __syncthreads();
    __bf16* hb = Ht + (size_t)n * CL;
    const int sub  = tid & 7;    // c-subrange (8 bf16 each)
    const int lrow = tid >> 3;   // 32 rows per pass
#pragma unroll
    for (int p = 0; p < 2; ++p) {
        int ll = p * 32 + lrow;
        bf16x8 v;
#pragma unroll
        for (int s = 0; s < 8; ++s) v[s] = (__bf16)T[ll][sub * 8 + s];
        *(bf16x8*)(hb + (size_t)(l0 + ll) * CCH + c0 + sub * 8) = v;
    }
}

// ---------------------------------------------------------------------------
// 4-weight fp32 -> bf16 convert, one launch. grid (256, 4).
// ---------------------------------------------------------------------------
__global__ __launch_bounds__(256) void tobf16_4(
    const float* __restrict__ s0, const float* __restrict__ s1,
    const float* __restrict__ s2, const float* __restrict__ s3,
    __bf16* __restrict__ dst) {
    const float* sp = (blockIdx.y == 0) ? s0 : (blockIdx.y == 1) ? s1
                    : (blockIdx.y == 2) ? s2 : s3;
    int i = (blockIdx.x * 256 + threadIdx.x) * 4;
    float4 v = *(const float4*)(sp + i);
    __bf16* d = dst + (size_t)blockIdx.y * CCH * CCH + i;
    d[0] = (__bf16)v.x; d[1] = (__bf16)v.y; d[2] = (__bf16)v.z; d[3] = (__bf16)v.w;
}

// ---------------------------------------------------------------------------
// bf16 MFMA GEMM, NT form, swizzled LDS.
// EPI: 2 +bias[m]->bf16, 4 +bias[m]+resid->fp32, 5 dual-bias[n] (QK fused)->bf16
// ---------------------------------------------------------------------------
#define BM 128
#define BN 128
#define BK 32

template<int EPI>
__global__ __launch_bounds__(256) void gemm_nt(
    const __bf16* __restrict__ A, const __bf16* __restrict__ B,
    void* __restrict__ Cv, int M, int N, int K,
    long bsA, long bsB, long bsC, long bsR,
    const float* __restrict__ bias, const float* __restrict__ bias2,
    const float* __restrict__ resid)
{
    __shared__ __align__(16) __bf16 As[BM * BK];
    __shared__ __align__(16) __bf16 Bs[BN * BK];
    const int tid = threadIdx.x;
    const int l = tid & 63, w = tid >> 6;
    const int wm = w >> 1, wn = w & 1;
    const int m0 = blockIdx.y * BM, n0 = blockIdx.x * BN;
    A += (long)blockIdx.z * bsA;
    B += (long)blockIdx.z * bsB;

    f32x4 acc[4][4];
#pragma unroll
    for (int i = 0; i < 4; ++i)
#pragma unroll
        for (int j = 0; j < 4; ++j) acc[i][j] = f32x4{0.f, 0.f, 0.f, 0.f};

    int jj, cc; swz_src(l, jj, cc);
    const int slot = swz_slot(l & 15, l >> 4);

    const __bf16* Ag = A + (size_t)(m0 + w * 16 + jj) * K + cc * 8;
    const __bf16* Bg = B + (size_t)(n0 + w * 16 + jj) * K + cc * 8;
    char* AsB = (char*)As + w * 1024;
    char* BsB = (char*)Bs + w * 1024;

    for (int k0 = 0; k0 < K; k0 += BK) {
        GLOAD_LDS16(Ag + k0,                 AsB);
        GLOAD_LDS16(Ag + k0 + (size_t)64*K,  AsB + 4096);
        GLOAD_LDS16(Bg + k0,                 BsB);
        GLOAD_LDS16(Bg + k0 + (size_t)64*K,  BsB + 4096);
        __syncthreads();
        bf16x8 ar[4], br[4];
#pragma unroll
        for (int t = 0; t < 4; ++t) {
            ar[t] = *(const bf16x8*)(As + (wm*64 + t*16) * BK + slot * 8);
            br[t] = *(const bf16x8*)(Bs + (wn*64 + t*16) * BK + slot * 8);
        }
#pragma unroll
        for (int ti = 0; ti < 4; ++ti)
#pragma unroll
            for (int tj = 0; tj < 4; ++tj)
                acc[ti][tj] = __builtin_amdgcn_mfma_f32_16x16x32_bf16(
                    ar[ti], br[tj], acc[ti][tj], 0, 0, 0);
        __syncthreads();
    }

    const long cb = (long)blockIdx.z * bsC;
    // EPI==5: block N-span 128 never straddles the 512 boundary
    const float* bn = (EPI == 5) ? ((n0 < 512) ? bias : (bias2 - 512)) : nullptr;
#pragma unroll
    for (int ti = 0; ti < 4; ++ti) {
#pragma unroll
        for (int r = 0; r < 4; ++r) {
            int m = m0 + wm*64 + ti*16 + (l >> 4)*4 + r;
            float bv = (EPI == 2 || EPI == 4) ? bias[m] : 0.f;
#pragma unroll
            for (int tj = 0; tj < 4; ++tj) {
                int n = n0 + wn*64 + tj*16 + (l & 15);
                float v = acc[ti][tj][r];
                if (EPI == 5) v += bn[n];
                if (EPI == 2 || EPI == 4) v += bv;
                if (EPI == 4) {
                    float rs = resid[(long)blockIdx.z * bsR + (size_t)m * N + n];
                    ((float*)Cv)[cb + (size_t)m * N + n] = v + rs;
                } else {
                    ((__bf16*)Cv)[cb + (size_t)m * N + n] = (__bf16)v;
                }
            }
        }
    }
}

// ---------------------------------------------------------------------------
// Flash attention v14 = v7 (empirical best, 198us) with EXACTLY ONE change:
// B2 is a raw s_barrier preceded by lgkmcnt(0) only (no vmcnt drain, no
// sched_barrier pins). stageV stays in flight through B2 and drains at B3's
// __syncthreads with QK+expst+smx cover; wave arrival at B2 is no longer
// gated on each wave's stageV L2 tail (the per-iteration skew cost).
// v13 post-mortem: counted vmcnt bundled with 192 sched_barrier(0) pins
// (m141 failure mode) + stageK move = +25us; this round de-confounds.
// Hazards: Sm visibility = lgkm before barrier (kept); Ks WAR (stageK after
// B3 overwrites) = kf reads lgkm-drained at B2; Vs reads occur after B3
// (full drain); stageV(t+1) WAR on Vs = vf reads lgkm-drained at next B1.
// ---------------------------------------------------------------------------
#define PSTR 88

__global__ __launch_bounds__(512, 2) void flash_attn(
    const __bf16* __restrict__ QK, const __bf16* __restrict__ Vb,
    __bf16* __restrict__ Ot)
{
    __shared__ __align__(16) __bf16 Ks[16 * 64 * 32];   // [kc:16][j:64][k:32] 64 KB
    __shared__ __align__(16) __bf16 Vs[2 * 512 * 32];   // [jc:2][c:512][j:32] 64 KB
    __shared__ float  Sm[64 * 68];                      // k-half merge, 17 KB
    __shared__ __align__(16) __bf16 Ps[64 * PSTR];      // 11 KB
    __shared__ float Lp[64 * 2];                        // l partials per jh

    const int tid = threadIdx.x;
    const int l = tid & 63, w = tid >> 6;
    const int wi = w & 1, jh = (w >> 1) & 1, kh = w >> 2;
    const int g = l >> 4, c = l & 15;
    // XCD-pair batch pinning (verified r6: FETCH 139->41 MB)
    const int b = (blockIdx.x & 7) >> 1;
    const int qt = ((blockIdx.x >> 3) << 1) | (blockIdx.x & 1);
    const int i0 = qt * 64;
    const size_t bb2 = (size_t)b * LL * QSTR;   // QK batch base
    const size_t bb  = (size_t)b * CL;          // V/O batch base
    const float alpha = 0.044194173824159216f;  // 1/sqrt(512)

    int jj, cc; swz_src(l, jj, cc);
    const int slot = swz_slot(c, g);

    // Q fragments: wave owns rows [i0+wi*32,+32) (2 frags), k-half kh*256
    bf16x8 Qf[2][8];
    {
        const __bf16* Qg = QK + bb2 + (size_t)(i0 + wi*32 + c) * QSTR + kh*256 + g*8;
#pragma unroll
        for (int mi = 0; mi < 2; ++mi)
#pragma unroll
            for (int kc = 0; kc < 8; ++kc)
                Qf[mi][kc] = *(const bf16x8*)(Qg + (size_t)mi*16*QSTR + kc*32);
    }

    f32x4 Oacc[4][4];
#pragma unroll
    for (int mi = 0; mi < 4; ++mi)
#pragma unroll
        for (int ni = 0; ni < 4; ++ni) Oacc[mi][ni] = f32x4{0.f, 0.f, 0.f, 0.f};
    float l_r[4] = {0.f, 0.f, 0.f, 0.f};

    const __bf16* Kb = QK + bb2 + 512;   // K columns of fused buffer
    const __bf16* Vg = Vb + bb;

    // K staging: wave stages kc = {w, w+8}
    auto stageK = [&](int j0) {
#pragma unroll
        for (int q = 0; q < 2; ++q) {
            int kc = q * 8 + w;
#pragma unroll
            for (int p = 0; p < 4; ++p) {
                const __bf16* src = Kb + (size_t)(j0 + p*16 + jj) * QSTR + kc*32 + cc*8;
                GLOAD_LDS16(src, (char*)Ks + kc*4096 + p*1024);
            }
        }
    };
    // V staging: wave stages c-rows [w*64,+64)
    auto stageV = [&](int j0) {
#pragma unroll
        for (int jc = 0; jc < 2; ++jc)
#pragma unroll
            for (int p = 0; p < 4; ++p) {
                const __bf16* src = Vg + (size_t)(w*64 + p*16 + jj) * LL + j0 + jc*32 + cc*8;
                GLOAD_LDS16(src, (char*)Vs + jc*32768 + (w*64 + p*16)*64);
            }
    };

    // export partner frag mi=(1-kh) to Sm (v5 layout; uniform-branch static idx)
    auto expst = [&](const f32x4 (&Sx)[2]) {
        const int er0 = wi*32 + (1 - kh)*16 + g*4;
#pragma unroll
        for (int tj = 0; tj < 2; ++tj)
#pragma unroll
            for (int r = 0; r < 4; ++r)
                Sm[(er0 + r)*68 + (jh*2 + tj)*16 + c] = Sx[tj][r];
    };
    // merge + exp own rows mi=kh
    auto smx = [&](const f32x4 (&Sown)[2]) {
        const int row0 = wi*32 + kh*16 + g*4;
#pragma unroll
        for (int r = 0; r < 4; ++r) {
            float rs = 0.f;
#pragma unroll
            for (int tj = 0; tj < 2; ++tj) {
                float p = __expf((Sown[tj][r] + Sm[(row0 + r)*68 + (jh*2 + tj)*16 + c]) * alpha);
                rs += p;
                Ps[(row0 + r) * PSTR + (jh*2 + tj)*16 + c] = (__bf16)p;
            }
            l_r[r] += rs;
        }
    };

    stageK(0);
    for (int t = 0; t < 64; ++t) {
        __syncthreads();             // B1: K(t) staged; prior PV done
        stageV(t * 64);              // in flight until B3 (QK + smx cover)

        // S partial: rows [wi*32,+32), cols [jh*32,+32), k-half kh
        f32x4 S[2][2];
#pragma unroll
        for (int mi = 0; mi < 2; ++mi)
#pragma unroll
            for (int tj = 0; tj < 2; ++tj) S[mi][tj] = f32x4{0.f,0.f,0.f,0.f};
        __builtin_amdgcn_s_setprio(1);
#pragma unroll
        for (int kc = 0; kc < 8; ++kc) {
#pragma unroll
            for (int tj = 0; tj < 2; ++tj) {
                bf16x8 kf = *(const bf16x8*)(Ks + (kh*8 + kc)*2048 + (jh*2 + tj)*512 + slot*8);
#pragma unroll
                for (int mi = 0; mi < 2; ++mi)
                    S[mi][tj] = __builtin_amdgcn_mfma_f32_16x16x32_bf16(Qf[mi][kc], kf, S[mi][tj], 0, 0, 0);
            }
        }
        __builtin_amdgcn_s_setprio(0);

        if (kh) expst(S[0]); else expst(S[1]);
        // B2: lgkm-only raw barrier — Sm visible, kf reads done;
        //     stageV's vmem stays in flight (drains at B3).
        asm volatile("s_waitcnt lgkmcnt(0)" ::: "memory");
        __builtin_amdgcn_s_barrier();

        if (kh) smx(S[1]); else smx(S[0]);
        __syncthreads();             // B3: Ps visible; stageV drained (vmcnt 0)

        if (t < 63) stageK((t + 1) * 64);   // drains at next B1 (PV cover)

        // O += P.V^T  (all 64 rows, c-slice [w*64,+64))
        __builtin_amdgcn_s_setprio(1);
#pragma unroll
        for (int jc = 0; jc < 2; ++jc) {
            bf16x8 pa[4];
#pragma unroll
            for (int mi = 0; mi < 4; ++mi)
                pa[mi] = *(const bf16x8*)(Ps + (mi*16 + c) * PSTR + jc*32 + g*8);
#pragma unroll
            for (int ni = 0; ni < 4; ++ni) {
                bf16x8 vf = *(const bf16x8*)(Vs + jc*16384 + (w*64 + ni*16)*32 + slot*8);
#pragma unroll
                for (int mi = 0; mi < 4; ++mi)
                    Oacc[mi][ni] = __builtin_amdgcn_mfma_f32_16x16x32_bf16(pa[mi], vf, Oacc[mi][ni], 0, 0, 0);
            }
        }
        __builtin_amdgcn_s_setprio(0);
    }

    // l: reduce lanes (c) then publish per-(row,jh) partial; combine in epilogue
#pragma unroll
    for (int r = 0; r < 4; ++r) {
        float tot = red_sum16(l_r[r]);
        if (c == 0) Lp[(wi*32 + kh*16 + g*4 + r)*2 + jh] = tot;
    }
    __syncthreads();
#pragma unroll
    for (int mi = 0; mi < 4; ++mi) {
#pragma unroll
        for (int r = 0; r < 4; ++r) {
            int row = mi*16 + g*4 + r;
            float inv = 1.f / (Lp[row*2] + Lp[row*2 + 1]);
#pragma unroll
            for (int ni = 0; ni < 4; ++ni) {
                int col = w*64 + ni*16 + c;
                Ot[bb + (size_t)(i0 + row) * CCH + col] = (__bf16)(Oacc[mi][ni][r] * inv);
            }
        }
    }
}

// ---------------------------------------------------------------------------
extern "C" void kernel_launch(void* const* d_in, const int* in_sizes, int n_in,
                              void* d_out, int out_size, void* d_ws, size_t ws_size,
                              hipStream_t stream) {
    const float* x   = (const float*)d_in[0];
    const float* gnw = (const float*)d_in[1];
    const float* gnb = (const float*)d_in[2];
    const float* wq  = (const float*)d_in[3];
    const float* bq  = (const float*)d_in[4];
    const float* wk  = (const float*)d_in[5];
    const float* bk  = (const float*)d_in[6];
    const float* wv  = (const float*)d_in[7];
    const float* bv  = (const float*)d_in[8];
    const float* wo  = (const float*)d_in[9];
    const float* bo  = (const float*)d_in[10];
    float* out = (float*)d_out;

    // ws (bf16): Ht | QK(2x) | Vb | Ot | Wb(4 weights) | stats  ~= 82 MiB
    __bf16* wsb = (__bf16*)d_ws;
    const size_t NCL = (size_t)NB * CL;
    __bf16* Ht  = wsb;
    __bf16* QKt = Ht + NCL;            // [NB][L][1024]
    __bf16* Vb  = QKt + 2 * NCL;
    __bf16* Ot  = Vb + NCL;
    __bf16* Wb  = Ot + NCL;            // wq|wk|wv|wo bf16, contiguous
    float* stats = (float*)(Wb + (size_t)4 * CCH * CCH);
    __bf16* wqkb = Wb;                             // [1024][512] stacked
    __bf16* wvb  = Wb + (size_t)2 * CCH * CCH;
    __bf16* wob  = Wb + (size_t)3 * CCH * CCH;

    tobf16_4<<<dim3(256, 4), 256, 0, stream>>>(wq, wk, wv, wo, Wb);
    gn_stats<<<NB * GRP, 1024, 0, stream>>>(x, stats);
    gn_norm_t<<<dim3(LL / 64, CCH / 64, NB), 256, 0, stream>>>(x, gnw, gnb, stats, Ht);

    // QK[l][0:512]=Q, [512:1024]=K  (M=L, N=1024, K=512), dual bias over n
    gemm_nt<5><<<dim3(1024 / 128, LL / 128, NB), 256, 0, stream>>>(
        Ht, wqkb, QKt, LL, 1024, CCH, CL, 0, (long)LL * 1024, 0, bq, bk, nullptr);
    // V[d][l] = Wv.Ht^T + bv  (M=C, N=L, K=C)
    gemm_nt<2><<<dim3(LL / 128, CCH / 128, NB), 256, 0, stream>>>(
        wvb, Ht, Vb, CCH, LL, CCH, 0, CL, CL, 0, bv, nullptr, nullptr);

    flash_attn<<<dim3(256), 512, 0, stream>>>(QKt, Vb, Ot);

    // out[d][l] = Wo.Ot^T + bo + x  (fp32 out)
    gemm_nt<4><<<dim3(LL / 128, CCH / 128, NB), 256, 0, stream>>>(
        wob, Ot, (void*)out, CCH, LL, CCH, 0, CL, CL, CL, bo, nullptr, x);
}

// Round 10
// 360.089 us; speedup vs baseline: 1.1011x; 1.1011x over previous
//
#include <hip/hip_runtime.h>
#include <math.h>

#define NB   4
#define CCH  512
#define LL   4096
#define GRP  32
#define CPG  16
#define CL   (CCH*LL)
#define EPSV 1e-5f
#define QSTR 1024   // QK fused row stride

typedef __bf16 bf16x8 __attribute__((ext_vector_type(8)));
typedef float  f32x4  __attribute__((ext_vector_type(4)));

#define GLOAD_LDS16(g, l) __builtin_amdgcn_global_load_lds( \
    (const __attribute__((address_space(1))) void*)(g),     \
    (__attribute__((address_space(3))) void*)(l), 16, 0, 0)

// ---------------------------------------------------------------------------
// Corrected XOR-swizzle (verified r6: conflicts 2.5e7 -> 6.3e6).
// ---------------------------------------------------------------------------
__device__ __forceinline__ int swz_slot(int row, int q) {
    return 4 * row + (q ^ ((row >> 1) & 3));
}
__device__ __forceinline__ void swz_src(int l, int& jj, int& cc) {
    jj = l >> 2;
    cc = (l & 3) ^ ((l >> 3) & 3);
}

#define DPPF(x, ctrl) __builtin_bit_cast(float, \
    __builtin_amdgcn_update_dpp(0, __builtin_bit_cast(int, (x)), (ctrl), 0xf, 0xf, false))
__device__ __forceinline__ float red_sum16(float x) {
    x += DPPF(x, 0xB1); x += DPPF(x, 0x4E);
    x += DPPF(x, 0x124); x += DPPF(x, 0x128);
    return x;
}

// ---------------------------------------------------------------------------
// GroupNorm pass 1 (v15): 256 blocks — each handles HALF a (n,g) group so the
// whole 256-CU chip is active (was 128 blocks = half idle). Writes raw
// partial {s1,s2}; gn_norm_t merges the two halves inline.
// ---------------------------------------------------------------------------
__global__ __launch_bounds__(1024) void gn_stats(const float* __restrict__ x,
                                                 float* __restrict__ stats) {
    int gid = blockIdx.x >> 1, h = blockIdx.x & 1;
    int n = gid >> 5, g = gid & 31;
    size_t base = ((size_t)n * CCH + (size_t)g * CPG) * LL
                + (size_t)h * (CPG * LL / 2);
    const float4* xp = (const float4*)(x + base);
    const int NV = CPG * LL / 8;   // half-group, in float4
    int tid = threadIdx.x;
    float s1 = 0.f, s2 = 0.f;
    for (int i = tid; i < NV; i += 1024) {
        float4 v = xp[i];
        s1 += v.x + v.y + v.z + v.w;
        s2 += v.x*v.x + v.y*v.y + v.z*v.z + v.w*v.w;
    }
    __shared__ float red[32];
    for (int o = 32; o; o >>= 1) { s1 += __shfl_down(s1, o); s2 += __shfl_down(s2, o); }
    int lane = tid & 63, w = tid >> 6;
    if (!lane) { red[w] = s1; red[16 + w] = s2; }
    __syncthreads();
    if (tid == 0) {
        float a = 0.f, b = 0.f;
        for (int i = 0; i < 16; ++i) { a += red[i]; b += red[16 + i]; }
        stats[gid * 4 + h * 2]     = a;   // raw partial sums
        stats[gid * 4 + h * 2 + 1] = b;
    }
}

// ---------------------------------------------------------------------------
// GroupNorm pass 2 + transpose: x [C,L] fp32 -> Ht [L,C] bf16.
// v15: merges the two gn_stats partials inline (4 broadcast loads/channel);
// keeps v14's vectorized bf16x8 store (16B/lane, was scalar 2B).
// ---------------------------------------------------------------------------
__global__ __launch_bounds__(256) void gn_norm_t(const float* __restrict__ x,
    const float* __restrict__ gamma, const float* __restrict__ beta,
    const float* __restrict__ stats, __bf16* __restrict__ Ht) {
    __shared__ float T[64][65];
    int n = blockIdx.z, c0 = blockIdx.y * 64, l0 = blockIdx.x * 64;
    int tid = threadIdx.x;
    int lx = tid & 63, py = tid >> 6;
    const float* xb = x + (size_t)n * CL;
    const float inv_n = 1.f / (float)(CPG * LL);
#pragma unroll
    for (int p = 0; p < 16; ++p) {
        int cl = p * 4 + py;
        int c = c0 + cl;
        int g = c >> 4;
        const float* P = stats + (size_t)(n * GRP + g) * 4;
        float s1 = P[0] + P[2], s2 = P[1] + P[3];
        float mean = s1 * inv_n;
        float var  = s2 * inv_n - mean * mean;
        float rstd = rsqrtf(var + EPSV);
        float sc = gamma[c] * rstd, bi = beta[c] - mean * sc;
        float v = xb[(size_t)c * LL + l0 + lx];
        T[lx][cl] = v * sc + bi;
    }
    __syncthreads();
    __bf16* hb = Ht + (size_t)n * CL;
    const int sub  = tid & 7;    // c-subrange (8 bf16 each)
    const int lrow = tid >> 3;   // 32 rows per pass
#pragma unroll
    for (int p = 0; p < 2; ++p) {
        int ll = p * 32 + lrow;
        bf16x8 v;
#pragma unroll
        for (int s = 0; s < 8; ++s) v[s] = (__bf16)T[ll][sub * 8 + s];
        *(bf16x8*)(hb + (size_t)(l0 + ll) * CCH + c0 + sub * 8) = v;
    }
}

// ---------------------------------------------------------------------------
// 4-weight fp32 -> bf16 convert, one launch. grid (256, 4).
// ---------------------------------------------------------------------------
__global__ __launch_bounds__(256) void tobf16_4(
    const float* __restrict__ s0, const float* __restrict__ s1,
    const float* __restrict__ s2, const float* __restrict__ s3,
    __bf16* __restrict__ dst) {
    const float* sp = (blockIdx.y == 0) ? s0 : (blockIdx.y == 1) ? s1
                    : (blockIdx.y == 2) ? s2 : s3;
    int i = (blockIdx.x * 256 + threadIdx.x) * 4;
    float4 v = *(const float4*)(sp + i);
    __bf16* d = dst + (size_t)blockIdx.y * CCH * CCH + i;
    d[0] = (__bf16)v.x; d[1] = (__bf16)v.y; d[2] = (__bf16)v.z; d[3] = (__bf16)v.w;
}

// ---------------------------------------------------------------------------
// bf16 MFMA GEMM, NT form, swizzled LDS.
// EPI: 2 +bias[m]->bf16, 4 +bias[m]+resid->fp32, 5 dual-bias[n] (QK fused)->bf16
// ---------------------------------------------------------------------------
#define BM 128
#define BN 128
#define BK 32

template<int EPI>
__global__ __launch_bounds__(256) void gemm_nt(
    const __bf16* __restrict__ A, const __bf16* __restrict__ B,
    void* __restrict__ Cv, int M, int N, int K,
    long bsA, long bsB, long bsC, long bsR,
    const float* __restrict__ bias, const float* __restrict__ bias2,
    const float* __restrict__ resid)
{
    __shared__ __align__(16) __bf16 As[BM * BK];
    __shared__ __align__(16) __bf16 Bs[BN * BK];
    const int tid = threadIdx.x;
    const int l = tid & 63, w = tid >> 6;
    const int wm = w >> 1, wn = w & 1;
    const int m0 = blockIdx.y * BM, n0 = blockIdx.x * BN;
    A += (long)blockIdx.z * bsA;
    B += (long)blockIdx.z * bsB;

    f32x4 acc[4][4];
#pragma unroll
    for (int i = 0; i < 4; ++i)
#pragma unroll
        for (int j = 0; j < 4; ++j) acc[i][j] = f32x4{0.f, 0.f, 0.f, 0.f};

    int jj, cc; swz_src(l, jj, cc);
    const int slot = swz_slot(l & 15, l >> 4);

    const __bf16* Ag = A + (size_t)(m0 + w * 16 + jj) * K + cc * 8;
    const __bf16* Bg = B + (size_t)(n0 + w * 16 + jj) * K + cc * 8;
    char* AsB = (char*)As + w * 1024;
    char* BsB = (char*)Bs + w * 1024;

    for (int k0 = 0; k0 < K; k0 += BK) {
        GLOAD_LDS16(Ag + k0,                 AsB);
        GLOAD_LDS16(Ag + k0 + (size_t)64*K,  AsB + 4096);
        GLOAD_LDS16(Bg + k0,                 BsB);
        GLOAD_LDS16(Bg + k0 + (size_t)64*K,  BsB + 4096);
        __syncthreads();
        bf16x8 ar[4], br[4];
#pragma unroll
        for (int t = 0; t < 4; ++t) {
            ar[t] = *(const bf16x8*)(As + (wm*64 + t*16) * BK + slot * 8);
            br[t] = *(const bf16x8*)(Bs + (wn*64 + t*16) * BK + slot * 8);
        }
#pragma unroll
        for (int ti = 0; ti < 4; ++ti)
#pragma unroll
            for (int tj = 0; tj < 4; ++tj)
                acc[ti][tj] = __builtin_amdgcn_mfma_f32_16x16x32_bf16(
                    ar[ti], br[tj], acc[ti][tj], 0, 0, 0);
        __syncthreads();
    }

    const long cb = (long)blockIdx.z * bsC;
    // EPI==5: block N-span 128 never straddles the 512 boundary
    const float* bn = (EPI == 5) ? ((n0 < 512) ? bias : (bias2 - 512)) : nullptr;
#pragma unroll
    for (int ti = 0; ti < 4; ++ti) {
#pragma unroll
        for (int r = 0; r < 4; ++r) {
            int m = m0 + wm*64 + ti*16 + (l >> 4)*4 + r;
            float bv = (EPI == 2 || EPI == 4) ? bias[m] : 0.f;
#pragma unroll
            for (int tj = 0; tj < 4; ++tj) {
                int n = n0 + wn*64 + tj*16 + (l & 15);
                float v = acc[ti][tj][r];
                if (EPI == 5) v += bn[n];
                if (EPI == 2 || EPI == 4) v += bv;
                if (EPI == 4) {
                    float rs = resid[(long)blockIdx.z * bsR + (size_t)m * N + n];
                    ((float*)Cv)[cb + (size_t)m * N + n] = v + rs;
                } else {
                    ((__bf16*)Cv)[cb + (size_t)m * N + n] = (__bf16)v;
                }
            }
        }
    }
}

// ---------------------------------------------------------------------------
// Flash attention v15 = v7 VERBATIM (empirical best, 198.1us). Session record:
// v8 (V->reg) +16, v9 (dbuf/2bar) +62, v10 (2blk/CU) +142, v11 (wave-local
// SM) +20, v12 (stageK@B2) +18, v13 (counted vmcnt+pins) +25, v14 (lgkm-only
// B2) +29 — ALL perturbations of v7 regress. v7's __syncthreads placement
// gives every staged load exactly one compute phase of cover and the
// compiler's natural schedule around it beats every hand-pinned variant.
// Declared structural floor for this structure.
// ---------------------------------------------------------------------------
#define PSTR 88

__global__ __launch_bounds__(512, 2) void flash_attn(
    const __bf16* __restrict__ QK, const __bf16* __restrict__ Vb,
    __bf16* __restrict__ Ot)
{
    __shared__ __align__(16) __bf16 Ks[16 * 64 * 32];   // [kc:16][j:64][k:32] 64 KB
    __shared__ __align__(16) __bf16 Vs[2 * 512 * 32];   // [jc:2][c:512][j:32] 64 KB
    __shared__ float  Sm[64 * 68];                      // k-half merge, 17 KB
    __shared__ __align__(16) __bf16 Ps[64 * PSTR];      // 11 KB
    __shared__ float Lp[64 * 2];                        // l partials per jh

    const int tid = threadIdx.x;
    const int l = tid & 63, w = tid >> 6;
    const int wi = w & 1, jh = (w >> 1) & 1, kh = w >> 2;
    const int g = l >> 4, c = l & 15;
    // XCD-pair batch pinning (verified r6: FETCH 139->41 MB)
    const int b = (blockIdx.x & 7) >> 1;
    const int qt = ((blockIdx.x >> 3) << 1) | (blockIdx.x & 1);
    const int i0 = qt * 64;
    const size_t bb2 = (size_t)b * LL * QSTR;   // QK batch base
    const size_t bb  = (size_t)b * CL;          // V/O batch base
    const float alpha = 0.044194173824159216f;  // 1/sqrt(512)

    int jj, cc; swz_src(l, jj, cc);
    const int slot = swz_slot(c, g);

    // Q fragments: wave owns rows [i0+wi*32,+32) (2 frags), k-half kh*256
    bf16x8 Qf[2][8];
    {
        const __bf16* Qg = QK + bb2 + (size_t)(i0 + wi*32 + c) * QSTR + kh*256 + g*8;
#pragma unroll
        for (int mi = 0; mi < 2; ++mi)
#pragma unroll
            for (int kc = 0; kc < 8; ++kc)
                Qf[mi][kc] = *(const bf16x8*)(Qg + (size_t)mi*16*QSTR + kc*32);
    }

    f32x4 Oacc[4][4];
#pragma unroll
    for (int mi = 0; mi < 4; ++mi)
#pragma unroll
        for (int ni = 0; ni < 4; ++ni) Oacc[mi][ni] = f32x4{0.f, 0.f, 0.f, 0.f};
    float l_r[4] = {0.f, 0.f, 0.f, 0.f};

    const __bf16* Kb = QK + bb2 + 512;   // K columns of fused buffer
    const __bf16* Vg = Vb + bb;

    // K staging: wave stages kc = {w, w+8}
    auto stageK = [&](int j0) {
#pragma unroll
        for (int q = 0; q < 2; ++q) {
            int kc = q * 8 + w;
#pragma unroll
            for (int p = 0; p < 4; ++p) {
                const __bf16* src = Kb + (size_t)(j0 + p*16 + jj) * QSTR + kc*32 + cc*8;
                GLOAD_LDS16(src, (char*)Ks + kc*4096 + p*1024);
            }
        }
    };
    // V staging: wave stages c-rows [w*64,+64)
    auto stageV = [&](int j0) {
#pragma unroll
        for (int jc = 0; jc < 2; ++jc)
#pragma unroll
            for (int p = 0; p < 4; ++p) {
                const __bf16* src = Vg + (size_t)(w*64 + p*16 + jj) * LL + j0 + jc*32 + cc*8;
                GLOAD_LDS16(src, (char*)Vs + jc*32768 + (w*64 + p*16)*64);
            }
    };

    // export partner frag mi=(1-kh) to Sm (v5 layout; uniform-branch static idx)
    auto expst = [&](const f32x4 (&Sx)[2]) {
        const int er0 = wi*32 + (1 - kh)*16 + g*4;
#pragma unroll
        for (int tj = 0; tj < 2; ++tj)
#pragma unroll
            for (int r = 0; r < 4; ++r)
                Sm[(er0 + r)*68 + (jh*2 + tj)*16 + c] = Sx[tj][r];
    };
    // merge + exp own rows mi=kh
    auto smx = [&](const f32x4 (&Sown)[2]) {
        const int row0 = wi*32 + kh*16 + g*4;
#pragma unroll
        for (int r = 0; r < 4; ++r) {
            float rs = 0.f;
#pragma unroll
            for (int tj = 0; tj < 2; ++tj) {
                float p = __expf((Sown[tj][r] + Sm[(row0 + r)*68 + (jh*2 + tj)*16 + c]) * alpha);
                rs += p;
                Ps[(row0 + r) * PSTR + (jh*2 + tj)*16 + c] = (__bf16)p;
            }
            l_r[r] += rs;
        }
    };

    stageK(0);
    for (int t = 0; t < 64; ++t) {
        __syncthreads();             // B1: K(t) staged; prior PV done
        stageV(t * 64);              // drains at B2

        // S partial: rows [wi*32,+32), cols [jh*32,+32), k-half kh
        f32x4 S[2][2];
#pragma unroll
        for (int mi = 0; mi < 2; ++mi)
#pragma unroll
            for (int tj = 0; tj < 2; ++tj) S[mi][tj] = f32x4{0.f,0.f,0.f,0.f};
        __builtin_amdgcn_s_setprio(1);
#pragma unroll
        for (int kc = 0; kc < 8; ++kc) {
#pragma unroll
            for (int tj = 0; tj < 2; ++tj) {
                bf16x8 kf = *(const bf16x8*)(Ks + (kh*8 + kc)*2048 + (jh*2 + tj)*512 + slot*8);
#pragma unroll
                for (int mi = 0; mi < 2; ++mi)
                    S[mi][tj] = __builtin_amdgcn_mfma_f32_16x16x32_bf16(Qf[mi][kc], kf, S[mi][tj], 0, 0, 0);
            }
        }
        __builtin_amdgcn_s_setprio(0);

        if (kh) expst(S[0]); else expst(S[1]);
        __syncthreads();             // B2: Sm visible; V(t) drained; kf reads done

        if (kh) smx(S[1]); else smx(S[0]);
        __syncthreads();             // B3: Ps visible
        if (t < 63) stageK((t + 1) * 64);   // all waves; drains at next B1 (PV cover)

        // O += P.V^T  (all 64 rows, c-slice [w*64,+64))
        __builtin_amdgcn_s_setprio(1);
#pragma unroll
        for (int jc = 0; jc < 2; ++jc) {
            bf16x8 pa[4];
#pragma unroll
            for (int mi = 0; mi < 4; ++mi)
                pa[mi] = *(const bf16x8*)(Ps + (mi*16 + c) * PSTR + jc*32 + g*8);
#pragma unroll
            for (int ni = 0; ni < 4; ++ni) {
                bf16x8 vf = *(const bf16x8*)(Vs + jc*16384 + (w*64 + ni*16)*32 + slot*8);
#pragma unroll
                for (int mi = 0; mi < 4; ++mi)
                    Oacc[mi][ni] = __builtin_amdgcn_mfma_f32_16x16x32_bf16(pa[mi], vf, Oacc[mi][ni], 0, 0, 0);
            }
        }
        __builtin_amdgcn_s_setprio(0);
    }

    // l: reduce lanes (c) then publish per-(row,jh) partial; combine in epilogue
#pragma unroll
    for (int r = 0; r < 4; ++r) {
        float tot = red_sum16(l_r[r]);
        if (c == 0) Lp[(wi*32 + kh*16 + g*4 + r)*2 + jh] = tot;
    }
    __syncthreads();
#pragma unroll
    for (int mi = 0; mi < 4; ++mi) {
#pragma unroll
        for (int r = 0; r < 4; ++r) {
            int row = mi*16 + g*4 + r;
            float inv = 1.f / (Lp[row*2] + Lp[row*2 + 1]);
#pragma unroll
            for (int ni = 0; ni < 4; ++ni) {
                int col = w*64 + ni*16 + c;
                Ot[bb + (size_t)(i0 + row) * CCH + col] = (__bf16)(Oacc[mi][ni][r] * inv);
            }
        }
    }
}

// ---------------------------------------------------------------------------
extern "C" void kernel_launch(void* const* d_in, const int* in_sizes, int n_in,
                              void* d_out, int out_size, void* d_ws, size_t ws_size,
                              hipStream_t stream) {
    const float* x   = (const float*)d_in[0];
    const float* gnw = (const float*)d_in[1];
    const float* gnb = (const float*)d_in[2];
    const float* wq  = (const float*)d_in[3];
    const float* bq  = (const float*)d_in[4];
    const float* wk  = (const float*)d_in[5];
    const float* bk  = (const float*)d_in[6];
    const float* wv  = (const float*)d_in[7];
    const float* bv  = (const float*)d_in[8];
    const float* wo  = (const float*)d_in[9];
    const float* bo  = (const float*)d_in[10];
    float* out = (float*)d_out;

    // ws (bf16): Ht | QK(2x) | Vb | Ot | Wb(4 weights) | stats  ~= 82 MiB
    __bf16* wsb = (__bf16*)d_ws;
    const size_t NCL = (size_t)NB * CL;
    __bf16* Ht  = wsb;
    __bf16* QKt = Ht + NCL;            // [NB][L][1024]
    __bf16* Vb  = QKt + 2 * NCL;
    __bf16* Ot  = Vb + NCL;
    __bf16* Wb  = Ot + NCL;            // wq|wk|wv|wo bf16, contiguous
    float* stats = (float*)(Wb + (size_t)4 * CCH * CCH);  // [128][4] partials
    __bf16* wqkb = Wb;                             // [1024][512] stacked
    __bf16* wvb  = Wb + (size_t)2 * CCH * CCH;
    __bf16* wob  = Wb + (size_t)3 * CCH * CCH;

    tobf16_4<<<dim3(256, 4), 256, 0, stream>>>(wq, wk, wv, wo, Wb);
    gn_stats<<<NB * GRP * 2, 1024, 0, stream>>>(x, stats);
    gn_norm_t<<<dim3(LL / 64, CCH / 64, NB), 256, 0, stream>>>(x, gnw, gnb, stats, Ht);

    // QK[l][0:512]=Q, [512:1024]=K  (M=L, N=1024, K=512), dual bias over n
    gemm_nt<5><<<dim3(1024 / 128, LL / 128, NB), 256, 0, stream>>>(
        Ht, wqkb, QKt, LL, 1024, CCH, CL, 0, (long)LL * 1024, 0, bq, bk, nullptr);
    // V[d][l] = Wv.Ht^T + bv  (M=C, N=L, K=C)
    gemm_nt<2><<<dim3(LL / 128, CCH / 128, NB), 256, 0, stream>>>(
        wvb, Ht, Vb, CCH, LL, CCH, 0, CL, CL, 0, bv, nullptr, nullptr);

    flash_attn<<<dim3(256), 512, 0, stream>>>(QKt, Vb, Ot);

    // out[d][l] = Wo.Ot^T + bo + x  (fp32 out)
    gemm_nt<4><<<dim3(LL / 128, CCH / 128, NB), 256, 0, stream>>>(
        wob, Ot, (void*)out, CCH, LL, CCH, 0, CL, CL, CL, bo, nullptr, x);
}

// Round 11
// 358.529 us; speedup vs baseline: 1.1059x; 1.0044x over previous
//
#include <hip/hip_runtime.h>
#include <math.h>

#define NB   4
#define CCH  512
#define LL   4096
#define GRP  32
#define CPG  16
#define CL   (CCH*LL)
#define EPSV 1e-5f
#define QSTR 1024   // QK fused row stride

typedef __bf16 bf16x8 __attribute__((ext_vector_type(8)));
typedef float  f32x4  __attribute__((ext_vector_type(4)));

#define GLOAD_LDS16(g, l) __builtin_amdgcn_global_load_lds( \
    (const __attribute__((address_space(1))) void*)(g),     \
    (__attribute__((address_space(3))) void*)(l), 16, 0, 0)

// ---------------------------------------------------------------------------
// Corrected XOR-swizzle (verified r6: conflicts 2.5e7 -> 6.3e6).
// ---------------------------------------------------------------------------
__device__ __forceinline__ int swz_slot(int row, int q) {
    return 4 * row + (q ^ ((row >> 1) & 3));
}
__device__ __forceinline__ void swz_src(int l, int& jj, int& cc) {
    jj = l >> 2;
    cc = (l & 3) ^ ((l >> 3) & 3);
}

#define DPPF(x, ctrl) __builtin_bit_cast(float, \
    __builtin_amdgcn_update_dpp(0, __builtin_bit_cast(int, (x)), (ctrl), 0xf, 0xf, false))
__device__ __forceinline__ float red_sum16(float x) {
    x += DPPF(x, 0xB1); x += DPPF(x, 0x4E);
    x += DPPF(x, 0x124); x += DPPF(x, 0x128);
    return x;
}

// ---------------------------------------------------------------------------
// GroupNorm pass 1 (v15): 256 blocks — each handles HALF a (n,g) group so the
// whole 256-CU chip is active. Writes raw partial {s1,s2}; gn_norm_t merges.
// ---------------------------------------------------------------------------
__global__ __launch_bounds__(1024) void gn_stats(const float* __restrict__ x,
                                                 float* __restrict__ stats) {
    int gid = blockIdx.x >> 1, h = blockIdx.x & 1;
    int n = gid >> 5, g = gid & 31;
    size_t base = ((size_t)n * CCH + (size_t)g * CPG) * LL
                + (size_t)h * (CPG * LL / 2);
    const float4* xp = (const float4*)(x + base);
    const int NV = CPG * LL / 8;   // half-group, in float4
    int tid = threadIdx.x;
    float s1 = 0.f, s2 = 0.f;
    for (int i = tid; i < NV; i += 1024) {
        float4 v = xp[i];
        s1 += v.x + v.y + v.z + v.w;
        s2 += v.x*v.x + v.y*v.y + v.z*v.z + v.w*v.w;
    }
    __shared__ float red[32];
    for (int o = 32; o; o >>= 1) { s1 += __shfl_down(s1, o); s2 += __shfl_down(s2, o); }
    int lane = tid & 63, w = tid >> 6;
    if (!lane) { red[w] = s1; red[16 + w] = s2; }
    __syncthreads();
    if (tid == 0) {
        float a = 0.f, b = 0.f;
        for (int i = 0; i < 16; ++i) { a += red[i]; b += red[16 + i]; }
        stats[gid * 4 + h * 2]     = a;   // raw partial sums
        stats[gid * 4 + h * 2 + 1] = b;
    }
}

// ---------------------------------------------------------------------------
// GroupNorm pass 2 + transpose: x [C,L] fp32 -> Ht [L,C] bf16.
// v15: merges the two gn_stats partials inline; vectorized bf16x8 store.
// ---------------------------------------------------------------------------
__global__ __launch_bounds__(256) void gn_norm_t(const float* __restrict__ x,
    const float* __restrict__ gamma, const float* __restrict__ beta,
    const float* __restrict__ stats, __bf16* __restrict__ Ht) {
    __shared__ float T[64][65];
    int n = blockIdx.z, c0 = blockIdx.y * 64, l0 = blockIdx.x * 64;
    int tid = threadIdx.x;
    int lx = tid & 63, py = tid >> 6;
    const float* xb = x + (size_t)n * CL;
    const float inv_n = 1.f / (float)(CPG * LL);
#pragma unroll
    for (int p = 0; p < 16; ++p) {
        int cl = p * 4 + py;
        int c = c0 + cl;
        int g = c >> 4;
        const float* P = stats + (size_t)(n * GRP + g) * 4;
        float s1 = P[0] + P[2], s2 = P[1] + P[3];
        float mean = s1 * inv_n;
        float var  = s2 * inv_n - mean * mean;
        float rstd = rsqrtf(var + EPSV);
        float sc = gamma[c] * rstd, bi = beta[c] - mean * sc;
        float v = xb[(size_t)c * LL + l0 + lx];
        T[lx][cl] = v * sc + bi;
    }
    __syncthreads();
    __bf16* hb = Ht + (size_t)n * CL;
    const int sub  = tid & 7;    // c-subrange (8 bf16 each)
    const int lrow = tid >> 3;   // 32 rows per pass
#pragma unroll
    for (int p = 0; p < 2; ++p) {
        int ll = p * 32 + lrow;
        bf16x8 v;
#pragma unroll
        for (int s = 0; s < 8; ++s) v[s] = (__bf16)T[ll][sub * 8 + s];
        *(bf16x8*)(hb + (size_t)(l0 + ll) * CCH + c0 + sub * 8) = v;
    }
}

// ---------------------------------------------------------------------------
// 4-weight fp32 -> bf16 convert, one launch. grid (256, 4).
// ---------------------------------------------------------------------------
__global__ __launch_bounds__(256) void tobf16_4(
    const float* __restrict__ s0, const float* __restrict__ s1,
    const float* __restrict__ s2, const float* __restrict__ s3,
    __bf16* __restrict__ dst) {
    const float* sp = (blockIdx.y == 0) ? s0 : (blockIdx.y == 1) ? s1
                    : (blockIdx.y == 2) ? s2 : s3;
    int i = (blockIdx.x * 256 + threadIdx.x) * 4;
    float4 v = *(const float4*)(sp + i);
    __bf16* d = dst + (size_t)blockIdx.y * CCH * CCH + i;
    d[0] = (__bf16)v.x; d[1] = (__bf16)v.y; d[2] = (__bf16)v.z; d[3] = (__bf16)v.w;
}

// ---------------------------------------------------------------------------
// bf16 MFMA GEMM, NT form, swizzled LDS.
// v16: BK=64 as two 32-k panels staged per barrier pair — halves the K-loop
// barrier count (K=512: 16->8 sync pairs). Panel layout/swizzle byte-identical
// to the proven BK=32 scheme; LDS 16->32 KB (still >=3 blocks/CU; m132's
// regression was at 64 KB). Per-panel frag loop keeps 8 bf16x8 live.
// EPI: 2 +bias[m]->bf16, 4 +bias[m]+resid->fp32, 5 dual-bias[n] (QK fused)->bf16
// ---------------------------------------------------------------------------
#define BM 128
#define BN 128
#define BK 64

template<int EPI>
__global__ __launch_bounds__(256) void gemm_nt(
    const __bf16* __restrict__ A, const __bf16* __restrict__ B,
    void* __restrict__ Cv, int M, int N, int K,
    long bsA, long bsB, long bsC, long bsR,
    const float* __restrict__ bias, const float* __restrict__ bias2,
    const float* __restrict__ resid)
{
    __shared__ __align__(16) __bf16 As[2 * BM * 32];   // [panel][128][32] 16 KB
    __shared__ __align__(16) __bf16 Bs[2 * BN * 32];
    const int tid = threadIdx.x;
    const int l = tid & 63, w = tid >> 6;
    const int wm = w >> 1, wn = w & 1;
    const int m0 = blockIdx.y * BM, n0 = blockIdx.x * BN;
    A += (long)blockIdx.z * bsA;
    B += (long)blockIdx.z * bsB;

    f32x4 acc[4][4];
#pragma unroll
    for (int i = 0; i < 4; ++i)
#pragma unroll
        for (int j = 0; j < 4; ++j) acc[i][j] = f32x4{0.f, 0.f, 0.f, 0.f};

    int jj, cc; swz_src(l, jj, cc);
    const int slot = swz_slot(l & 15, l >> 4);

    const __bf16* Ag = A + (size_t)(m0 + w * 16 + jj) * K + cc * 8;
    const __bf16* Bg = B + (size_t)(n0 + w * 16 + jj) * K + cc * 8;
    char* AsB = (char*)As + w * 1024;
    char* BsB = (char*)Bs + w * 1024;

    for (int k0 = 0; k0 < K; k0 += BK) {
        // panel 0: k in [k0, k0+32)
        GLOAD_LDS16(Ag + k0,                      AsB);
        GLOAD_LDS16(Ag + k0 + (size_t)64*K,       AsB + 4096);
        GLOAD_LDS16(Bg + k0,                      BsB);
        GLOAD_LDS16(Bg + k0 + (size_t)64*K,       BsB + 4096);
        // panel 1: k in [k0+32, k0+64)
        GLOAD_LDS16(Ag + k0 + 32,                 AsB + 8192);
        GLOAD_LDS16(Ag + k0 + 32 + (size_t)64*K,  AsB + 8192 + 4096);
        GLOAD_LDS16(Bg + k0 + 32,                 BsB + 8192);
        GLOAD_LDS16(Bg + k0 + 32 + (size_t)64*K,  BsB + 8192 + 4096);
        __syncthreads();
#pragma unroll
        for (int h = 0; h < 2; ++h) {
            bf16x8 ar[4], br[4];
#pragma unroll
            for (int t = 0; t < 4; ++t) {
                ar[t] = *(const bf16x8*)(As + h*4096 + (wm*64 + t*16) * 32 + slot * 8);
                br[t] = *(const bf16x8*)(Bs + h*4096 + (wn*64 + t*16) * 32 + slot * 8);
            }
#pragma unroll
            for (int ti = 0; ti < 4; ++ti)
#pragma unroll
                for (int tj = 0; tj < 4; ++tj)
                    acc[ti][tj] = __builtin_amdgcn_mfma_f32_16x16x32_bf16(
                        ar[ti], br[tj], acc[ti][tj], 0, 0, 0);
        }
        __syncthreads();
    }

    const long cb = (long)blockIdx.z * bsC;
    // EPI==5: block N-span 128 never straddles the 512 boundary
    const float* bn = (EPI == 5) ? ((n0 < 512) ? bias : (bias2 - 512)) : nullptr;
#pragma unroll
    for (int ti = 0; ti < 4; ++ti) {
#pragma unroll
        for (int r = 0; r < 4; ++r) {
            int m = m0 + wm*64 + ti*16 + (l >> 4)*4 + r;
            float bv = (EPI == 2 || EPI == 4) ? bias[m] : 0.f;
#pragma unroll
            for (int tj = 0; tj < 4; ++tj) {
                int n = n0 + wn*64 + tj*16 + (l & 15);
                float v = acc[ti][tj][r];
                if (EPI == 5) v += bn[n];
                if (EPI == 2 || EPI == 4) v += bv;
                if (EPI == 4) {
                    float rs = resid[(long)blockIdx.z * bsR + (size_t)m * N + n];
                    ((float*)Cv)[cb + (size_t)m * N + n] = v + rs;
                } else {
                    ((__bf16*)Cv)[cb + (size_t)m * N + n] = (__bf16)v;
                }
            }
        }
    }
}

// ---------------------------------------------------------------------------
// Flash attention v15 = v7 VERBATIM (empirical best). All 8 perturbations
// regressed (+16..+142us); declared structural floor for this structure.
// ---------------------------------------------------------------------------
#define PSTR 88

__global__ __launch_bounds__(512, 2) void flash_attn(
    const __bf16* __restrict__ QK, const __bf16* __restrict__ Vb,
    __bf16* __restrict__ Ot)
{
    __shared__ __align__(16) __bf16 Ks[16 * 64 * 32];   // [kc:16][j:64][k:32] 64 KB
    __shared__ __align__(16) __bf16 Vs[2 * 512 * 32];   // [jc:2][c:512][j:32] 64 KB
    __shared__ float  Sm[64 * 68];                      // k-half merge, 17 KB
    __shared__ __align__(16) __bf16 Ps[64 * PSTR];      // 11 KB
    __shared__ float Lp[64 * 2];                        // l partials per jh

    const int tid = threadIdx.x;
    const int l = tid & 63, w = tid >> 6;
    const int wi = w & 1, jh = (w >> 1) & 1, kh = w >> 2;
    const int g = l >> 4, c = l & 15;
    // XCD-pair batch pinning (verified r6: FETCH 139->41 MB)
    const int b = (blockIdx.x & 7) >> 1;
    const int qt = ((blockIdx.x >> 3) << 1) | (blockIdx.x & 1);
    const int i0 = qt * 64;
    const size_t bb2 = (size_t)b * LL * QSTR;   // QK batch base
    const size_t bb  = (size_t)b * CL;          // V/O batch base
    const float alpha = 0.044194173824159216f;  // 1/sqrt(512)

    int jj, cc; swz_src(l, jj, cc);
    const int slot = swz_slot(c, g);

    // Q fragments: wave owns rows [i0+wi*32,+32) (2 frags), k-half kh*256
    bf16x8 Qf[2][8];
    {
        const __bf16* Qg = QK + bb2 + (size_t)(i0 + wi*32 + c) * QSTR + kh*256 + g*8;
#pragma unroll
        for (int mi = 0; mi < 2; ++mi)
#pragma unroll
            for (int kc = 0; kc < 8; ++kc)
                Qf[mi][kc] = *(const bf16x8*)(Qg + (size_t)mi*16*QSTR + kc*32);
    }

    f32x4 Oacc[4][4];
#pragma unroll
    for (int mi = 0; mi < 4; ++mi)
#pragma unroll
        for (int ni = 0; ni < 4; ++ni) Oacc[mi][ni] = f32x4{0.f, 0.f, 0.f, 0.f};
    float l_r[4] = {0.f, 0.f, 0.f, 0.f};

    const __bf16* Kb = QK + bb2 + 512;   // K columns of fused buffer
    const __bf16* Vg = Vb + bb;

    // K staging: wave stages kc = {w, w+8}
    auto stageK = [&](int j0) {
#pragma unroll
        for (int q = 0; q < 2; ++q) {
            int kc = q * 8 + w;
#pragma unroll
            for (int p = 0; p < 4; ++p) {
                const __bf16* src = Kb + (size_t)(j0 + p*16 + jj) * QSTR + kc*32 + cc*8;
                GLOAD_LDS16(src, (char*)Ks + kc*4096 + p*1024);
            }
        }
    };
    // V staging: wave stages c-rows [w*64,+64)
    auto stageV = [&](int j0) {
#pragma unroll
        for (int jc = 0; jc < 2; ++jc)
#pragma unroll
            for (int p = 0; p < 4; ++p) {
                const __bf16* src = Vg + (size_t)(w*64 + p*16 + jj) * LL + j0 + jc*32 + cc*8;
                GLOAD_LDS16(src, (char*)Vs + jc*32768 + (w*64 + p*16)*64);
            }
    };

    // export partner frag mi=(1-kh) to Sm (v5 layout; uniform-branch static idx)
    auto expst = [&](const f32x4 (&Sx)[2]) {
        const int er0 = wi*32 + (1 - kh)*16 + g*4;
#pragma unroll
        for (int tj = 0; tj < 2; ++tj)
#pragma unroll
            for (int r = 0; r < 4; ++r)
                Sm[(er0 + r)*68 + (jh*2 + tj)*16 + c] = Sx[tj][r];
    };
    // merge + exp own rows mi=kh
    auto smx = [&](const f32x4 (&Sown)[2]) {
        const int row0 = wi*32 + kh*16 + g*4;
#pragma unroll
        for (int r = 0; r < 4; ++r) {
            float rs = 0.f;
#pragma unroll
            for (int tj = 0; tj < 2; ++tj) {
                float p = __expf((Sown[tj][r] + Sm[(row0 + r)*68 + (jh*2 + tj)*16 + c]) * alpha);
                rs += p;
                Ps[(row0 + r) * PSTR + (jh*2 + tj)*16 + c] = (__bf16)p;
            }
            l_r[r] += rs;
        }
    };

    stageK(0);
    for (int t = 0; t < 64; ++t) {
        __syncthreads();             // B1: K(t) staged; prior PV done
        stageV(t * 64);              // drains at B2

        // S partial: rows [wi*32,+32), cols [jh*32,+32), k-half kh
        f32x4 S[2][2];
#pragma unroll
        for (int mi = 0; mi < 2; ++mi)
#pragma unroll
            for (int tj = 0; tj < 2; ++tj) S[mi][tj] = f32x4{0.f,0.f,0.f,0.f};
        __builtin_amdgcn_s_setprio(1);
#pragma unroll
        for (int kc = 0; kc < 8; ++kc) {
#pragma unroll
            for (int tj = 0; tj < 2; ++tj) {
                bf16x8 kf = *(const bf16x8*)(Ks + (kh*8 + kc)*2048 + (jh*2 + tj)*512 + slot*8);
#pragma unroll
                for (int mi = 0; mi < 2; ++mi)
                    S[mi][tj] = __builtin_amdgcn_mfma_f32_16x16x32_bf16(Qf[mi][kc], kf, S[mi][tj], 0, 0, 0);
            }
        }
        __builtin_amdgcn_s_setprio(0);

        if (kh) expst(S[0]); else expst(S[1]);
        __syncthreads();             // B2: Sm visible; V(t) drained; kf reads done

        if (kh) smx(S[1]); else smx(S[0]);
        __syncthreads();             // B3: Ps visible
        if (t < 63) stageK((t + 1) * 64);   // all waves; drains at next B1 (PV cover)

        // O += P.V^T  (all 64 rows, c-slice [w*64,+64))
        __builtin_amdgcn_s_setprio(1);
#pragma unroll
        for (int jc = 0; jc < 2; ++jc) {
            bf16x8 pa[4];
#pragma unroll
            for (int mi = 0; mi < 4; ++mi)
                pa[mi] = *(const bf16x8*)(Ps + (mi*16 + c) * PSTR + jc*32 + g*8);
#pragma unroll
            for (int ni = 0; ni < 4; ++ni) {
                bf16x8 vf = *(const bf16x8*)(Vs + jc*16384 + (w*64 + ni*16)*32 + slot*8);
#pragma unroll
                for (int mi = 0; mi < 4; ++mi)
                    Oacc[mi][ni] = __builtin_amdgcn_mfma_f32_16x16x32_bf16(pa[mi], vf, Oacc[mi][ni], 0, 0, 0);
            }
        }
        __builtin_amdgcn_s_setprio(0);
    }

    // l: reduce lanes (c) then publish per-(row,jh) partial; combine in epilogue
#pragma unroll
    for (int r = 0; r < 4; ++r) {
        float tot = red_sum16(l_r[r]);
        if (c == 0) Lp[(wi*32 + kh*16 + g*4 + r)*2 + jh] = tot;
    }
    __syncthreads();
#pragma unroll
    for (int mi = 0; mi < 4; ++mi) {
#pragma unroll
        for (int r = 0; r < 4; ++r) {
            int row = mi*16 + g*4 + r;
            float inv = 1.f / (Lp[row*2] + Lp[row*2 + 1]);
#pragma unroll
            for (int ni = 0; ni < 4; ++ni) {
                int col = w*64 + ni*16 + c;
                Ot[bb + (size_t)(i0 + row) * CCH + col] = (__bf16)(Oacc[mi][ni][r] * inv);
            }
        }
    }
}

// ---------------------------------------------------------------------------
extern "C" void kernel_launch(void* const* d_in, const int* in_sizes, int n_in,
                              void* d_out, int out_size, void* d_ws, size_t ws_size,
                              hipStream_t stream) {
    const float* x   = (const float*)d_in[0];
    const float* gnw = (const float*)d_in[1];
    const float* gnb = (const float*)d_in[2];
    const float* wq  = (const float*)d_in[3];
    const float* bq  = (const float*)d_in[4];
    const float* wk  = (const float*)d_in[5];
    const float* bk  = (const float*)d_in[6];
    const float* wv  = (const float*)d_in[7];
    const float* bv  = (const float*)d_in[8];
    const float* wo  = (const float*)d_in[9];
    const float* bo  = (const float*)d_in[10];
    float* out = (float*)d_out;

    // ws (bf16): Ht | QK(2x) | Vb | Ot | Wb(4 weights) | stats  ~= 82 MiB
    __bf16* wsb = (__bf16*)d_ws;
    const size_t NCL = (size_t)NB * CL;
    __bf16* Ht  = wsb;
    __bf16* QKt = Ht + NCL;            // [NB][L][1024]
    __bf16* Vb  = QKt + 2 * NCL;
    __bf16* Ot  = Vb + NCL;
    __bf16* Wb  = Ot + NCL;            // wq|wk|wv|wo bf16, contiguous
    float* stats = (float*)(Wb + (size_t)4 * CCH * CCH);  // [128][4] partials
    __bf16* wqkb = Wb;                             // [1024][512] stacked
    __bf16* wvb  = Wb + (size_t)2 * CCH * CCH;
    __bf16* wob  = Wb + (size_t)3 * CCH * CCH;

    tobf16_4<<<dim3(256, 4), 256, 0, stream>>>(wq, wk, wv, wo, Wb);
    gn_stats<<<NB * GRP * 2, 1024, 0, stream>>>(x, stats);
    gn_norm_t<<<dim3(LL / 64, CCH / 64, NB), 256, 0, stream>>>(x, gnw, gnb, stats, Ht);

    // QK[l][0:512]=Q, [512:1024]=K  (M=L, N=1024, K=512), dual bias over n
    gemm_nt<5><<<dim3(1024 / 128, LL / 128, NB), 256, 0, stream>>>(
        Ht, wqkb, QKt, LL, 1024, CCH, CL, 0, (long)LL * 1024, 0, bq, bk, nullptr);
    // V[d][l] = Wv.Ht^T + bv  (M=C, N=L, K=C)
    gemm_nt<2><<<dim3(LL / 128, CCH / 128, NB), 256, 0, stream>>>(
        wvb, Ht, Vb, CCH, LL, CCH, 0, CL, CL, 0, bv, nullptr, nullptr);

    flash_attn<<<dim3(256), 512, 0, stream>>>(QKt, Vb, Ot);

    // out[d][l] = Wo.Ot^T + bo + x  (fp32 out)
    gemm_nt<4><<<dim3(LL / 128, CCH / 128, NB), 256, 0, stream>>>(
        wob, Ot, (void*)out, CCH, LL, CCH, 0, CL, CL, CL, bo, nullptr, x);
}

// Round 12
// 349.977 us; speedup vs baseline: 1.1329x; 1.0244x over previous
//
#include <hip/hip_runtime.h>
#include <math.h>

#define NB   4
#define CCH  512
#define LL   4096
#define GRP  32
#define CPG  16
#define CL   (CCH*LL)
#define EPSV 1e-5f
#define QSTR 1024   // QK fused row stride

typedef __bf16 bf16x8 __attribute__((ext_vector_type(8)));
typedef float  f32x4  __attribute__((ext_vector_type(4)));

#define GLOAD_LDS16(g, l) __builtin_amdgcn_global_load_lds( \
    (const __attribute__((address_space(1))) void*)(g),     \
    (__attribute__((address_space(3))) void*)(l), 16, 0, 0)

// ---------------------------------------------------------------------------
// Corrected XOR-swizzle (verified r6: conflicts 2.5e7 -> 6.3e6).
// ---------------------------------------------------------------------------
__device__ __forceinline__ int swz_slot(int row, int q) {
    return 4 * row + (q ^ ((row >> 1) & 3));
}
__device__ __forceinline__ void swz_src(int l, int& jj, int& cc) {
    jj = l >> 2;
    cc = (l & 3) ^ ((l >> 3) & 3);
}

#define DPPF(x, ctrl) __builtin_bit_cast(float, \
    __builtin_amdgcn_update_dpp(0, __builtin_bit_cast(int, (x)), (ctrl), 0xf, 0xf, false))
__device__ __forceinline__ float red_sum16(float x) {
    x += DPPF(x, 0xB1); x += DPPF(x, 0x4E);
    x += DPPF(x, 0x124); x += DPPF(x, 0x128);
    return x;
}

// ---------------------------------------------------------------------------
// GroupNorm pass 1 (v15): 256 blocks — each handles HALF a (n,g) group so the
// whole 256-CU chip is active. Writes raw partial {s1,s2}; gn_norm_t merges.
// ---------------------------------------------------------------------------
__global__ __launch_bounds__(1024) void gn_stats(const float* __restrict__ x,
                                                 float* __restrict__ stats) {
    int gid = blockIdx.x >> 1, h = blockIdx.x & 1;
    int n = gid >> 5, g = gid & 31;
    size_t base = ((size_t)n * CCH + (size_t)g * CPG) * LL
                + (size_t)h * (CPG * LL / 2);
    const float4* xp = (const float4*)(x + base);
    const int NV = CPG * LL / 8;   // half-group, in float4
    int tid = threadIdx.x;
    float s1 = 0.f, s2 = 0.f;
    for (int i = tid; i < NV; i += 1024) {
        float4 v = xp[i];
        s1 += v.x + v.y + v.z + v.w;
        s2 += v.x*v.x + v.y*v.y + v.z*v.z + v.w*v.w;
    }
    __shared__ float red[32];
    for (int o = 32; o; o >>= 1) { s1 += __shfl_down(s1, o); s2 += __shfl_down(s2, o); }
    int lane = tid & 63, w = tid >> 6;
    if (!lane) { red[w] = s1; red[16 + w] = s2; }
    __syncthreads();
    if (tid == 0) {
        float a = 0.f, b = 0.f;
        for (int i = 0; i < 16; ++i) { a += red[i]; b += red[16 + i]; }
        stats[gid * 4 + h * 2]     = a;   // raw partial sums
        stats[gid * 4 + h * 2 + 1] = b;
    }
}

// ---------------------------------------------------------------------------
// GroupNorm pass 2 + transpose: x [C,L] fp32 -> Ht [L,C] bf16.
// v15: merges the two gn_stats partials inline; vectorized bf16x8 store.
// ---------------------------------------------------------------------------
__global__ __launch_bounds__(256) void gn_norm_t(const float* __restrict__ x,
    const float* __restrict__ gamma, const float* __restrict__ beta,
    const float* __restrict__ stats, __bf16* __restrict__ Ht) {
    __shared__ float T[64][65];
    int n = blockIdx.z, c0 = blockIdx.y * 64, l0 = blockIdx.x * 64;
    int tid = threadIdx.x;
    int lx = tid & 63, py = tid >> 6;
    const float* xb = x + (size_t)n * CL;
    const float inv_n = 1.f / (float)(CPG * LL);
#pragma unroll
    for (int p = 0; p < 16; ++p) {
        int cl = p * 4 + py;
        int c = c0 + cl;
        int g = c >> 4;
        const float* P = stats + (size_t)(n * GRP + g) * 4;
        float s1 = P[0] + P[2], s2 = P[1] + P[3];
        float mean = s1 * inv_n;
        float var  = s2 * inv_n - mean * mean;
        float rstd = rsqrtf(var + EPSV);
        float sc = gamma[c] * rstd, bi = beta[c] - mean * sc;
        float v = xb[(size_t)c * LL + l0 + lx];
        T[lx][cl] = v * sc + bi;
    }
    __syncthreads();
    __bf16* hb = Ht + (size_t)n * CL;
    const int sub  = tid & 7;    // c-subrange (8 bf16 each)
    const int lrow = tid >> 3;   // 32 rows per pass
#pragma unroll
    for (int p = 0; p < 2; ++p) {
        int ll = p * 32 + lrow;
        bf16x8 v;
#pragma unroll
        for (int s = 0; s < 8; ++s) v[s] = (__bf16)T[ll][sub * 8 + s];
        *(bf16x8*)(hb + (size_t)(l0 + ll) * CCH + c0 + sub * 8) = v;
    }
}

// ---------------------------------------------------------------------------
// 4-weight fp32 -> bf16 convert, one launch. grid (256, 4).
// ---------------------------------------------------------------------------
__global__ __launch_bounds__(256) void tobf16_4(
    const float* __restrict__ s0, const float* __restrict__ s1,
    const float* __restrict__ s2, const float* __restrict__ s3,
    __bf16* __restrict__ dst) {
    const float* sp = (blockIdx.y == 0) ? s0 : (blockIdx.y == 1) ? s1
                    : (blockIdx.y == 2) ? s2 : s3;
    int i = (blockIdx.x * 256 + threadIdx.x) * 4;
    float4 v = *(const float4*)(sp + i);
    __bf16* d = dst + (size_t)blockIdx.y * CCH * CCH + i;
    d[0] = (__bf16)v.x; d[1] = (__bf16)v.y; d[2] = (__bf16)v.z; d[3] = (__bf16)v.w;
}

// ---------------------------------------------------------------------------
// bf16 MFMA GEMM body, NT form, swizzled LDS, BK=64 (two 32-k panels).
// v17: factored to a device function so one kernel can host multiple GEMMs
// (tail-fill) with an XCD-chunked work-id mapping (T1).
// EPI: 2 +bias[m]->bf16, 4 +bias[m]+resid->fp32, 5 dual-bias[n] (QK fused)->bf16
// ---------------------------------------------------------------------------
#define BM 128
#define BN 128
#define BK 64

template<int EPI>
__device__ __forceinline__ void gemm_body(
    __bf16* As, __bf16* Bs,
    const __bf16* __restrict__ A, const __bf16* __restrict__ B,
    void* __restrict__ Cv, int M, int N, int K,
    long bsA, long bsB, long bsC, long bsR,
    const float* __restrict__ bias, const float* __restrict__ bias2,
    const float* __restrict__ resid,
    int bx, int by, int bz)
{
    const int tid = threadIdx.x;
    const int l = tid & 63, w = tid >> 6;
    const int wm = w >> 1, wn = w & 1;
    const int m0 = by * BM, n0 = bx * BN;
    A += (long)bz * bsA;
    B += (long)bz * bsB;

    f32x4 acc[4][4];
#pragma unroll
    for (int i = 0; i < 4; ++i)
#pragma unroll
        for (int j = 0; j < 4; ++j) acc[i][j] = f32x4{0.f, 0.f, 0.f, 0.f};

    int jj, cc; swz_src(l, jj, cc);
    const int slot = swz_slot(l & 15, l >> 4);

    const __bf16* Ag = A + (size_t)(m0 + w * 16 + jj) * K + cc * 8;
    const __bf16* Bg = B + (size_t)(n0 + w * 16 + jj) * K + cc * 8;
    char* AsB = (char*)As + w * 1024;
    char* BsB = (char*)Bs + w * 1024;

    for (int k0 = 0; k0 < K; k0 += BK) {
        GLOAD_LDS16(Ag + k0,                      AsB);
        GLOAD_LDS16(Ag + k0 + (size_t)64*K,       AsB + 4096);
        GLOAD_LDS16(Bg + k0,                      BsB);
        GLOAD_LDS16(Bg + k0 + (size_t)64*K,       BsB + 4096);
        GLOAD_LDS16(Ag + k0 + 32,                 AsB + 8192);
        GLOAD_LDS16(Ag + k0 + 32 + (size_t)64*K,  AsB + 8192 + 4096);
        GLOAD_LDS16(Bg + k0 + 32,                 BsB + 8192);
        GLOAD_LDS16(Bg + k0 + 32 + (size_t)64*K,  BsB + 8192 + 4096);
        __syncthreads();
#pragma unroll
        for (int h = 0; h < 2; ++h) {
            bf16x8 ar[4], br[4];
#pragma unroll
            for (int t = 0; t < 4; ++t) {
                ar[t] = *(const bf16x8*)(As + h*4096 + (wm*64 + t*16) * 32 + slot * 8);
                br[t] = *(const bf16x8*)(Bs + h*4096 + (wn*64 + t*16) * 32 + slot * 8);
            }
#pragma unroll
            for (int ti = 0; ti < 4; ++ti)
#pragma unroll
                for (int tj = 0; tj < 4; ++tj)
                    acc[ti][tj] = __builtin_amdgcn_mfma_f32_16x16x32_bf16(
                        ar[ti], br[tj], acc[ti][tj], 0, 0, 0);
        }
        __syncthreads();
    }

    const long cb = (long)bz * bsC;
    // EPI==5: block N-span 128 never straddles the 512 boundary
    const float* bn = (EPI == 5) ? ((n0 < 512) ? bias : (bias2 - 512)) : nullptr;
#pragma unroll
    for (int ti = 0; ti < 4; ++ti) {
#pragma unroll
        for (int r = 0; r < 4; ++r) {
            int m = m0 + wm*64 + ti*16 + (l >> 4)*4 + r;
            float bv = (EPI == 2 || EPI == 4) ? bias[m] : 0.f;
#pragma unroll
            for (int tj = 0; tj < 4; ++tj) {
                int n = n0 + wn*64 + tj*16 + (l & 15);
                float v = acc[ti][tj][r];
                if (EPI == 5) v += bn[n];
                if (EPI == 2 || EPI == 4) v += bv;
                if (EPI == 4) {
                    float rs = resid[(long)bz * bsR + (size_t)m * N + n];
                    ((float*)Cv)[cb + (size_t)m * N + n] = v + rs;
                } else {
                    ((__bf16*)Cv)[cb + (size_t)m * N + n] = (__bf16)v;
                }
            }
        }
    }
}

// ---------------------------------------------------------------------------
// v17: QK-GEMM (1024 work-ids) + V-GEMM (512 work-ids) in ONE 1536-block
// launch. Both depend only on Ht — merging fills each other's tail drain.
// XCD-chunked work mapping (T1, bijective: 1536%8==0): work = (d&7)*192+(d>>3)
// gives each XCD a contiguous 192-id chunk -> whole-B (2MB, L2-resident) +
// a contiguous A-panel slice (~3MB) read once per XCD (was: A streamed 16MB
// through EVERY XCD's L2 with the default %8 round-robin).
// ---------------------------------------------------------------------------
__global__ __launch_bounds__(256) void gemm_qkv(
    const __bf16* __restrict__ Ht, const __bf16* __restrict__ wqkb,
    __bf16* __restrict__ QKt, const __bf16* __restrict__ wvb,
    __bf16* __restrict__ Vb,
    const float* __restrict__ bq, const float* __restrict__ bk,
    const float* __restrict__ bv)
{
    __shared__ __align__(16) __bf16 As[2 * BM * 32];
    __shared__ __align__(16) __bf16 Bs[2 * BN * 32];
    const int d = blockIdx.x;
    const int wk = (d & 7) * 192 + (d >> 3);   // XCD-chunked work id
    if (wk < 1024) {
        // QK: M=L, N=1024, K=512; grid was (8, 32, 4)
        gemm_body<5>(As, Bs, Ht, wqkb, QKt, LL, 1024, CCH,
                     CL, 0, (long)LL * 1024, 0, bq, bk, nullptr,
                     wk & 7, (wk >> 3) & 31, wk >> 8);
    } else {
        // V: M=C, N=L, K=C; grid was (32, 4, 4)
        const int v = wk - 1024;
        gemm_body<2>(As, Bs, wvb, Ht, Vb, CCH, LL, CCH,
                     0, CL, CL, 0, bv, nullptr, nullptr,
                     v & 31, (v >> 5) & 3, v >> 7);
    }
}

// out GEMM (EPI=4), 512 blocks, same XCD-chunked mapping (chunk=64).
__global__ __launch_bounds__(256) void gemm_out(
    const __bf16* __restrict__ wob, const __bf16* __restrict__ Ot,
    float* __restrict__ out, const float* __restrict__ bo,
    const float* __restrict__ xr)
{
    __shared__ __align__(16) __bf16 As[2 * BM * 32];
    __shared__ __align__(16) __bf16 Bs[2 * BN * 32];
    const int d = blockIdx.x;
    const int wk = (d & 7) * 64 + (d >> 3);
    gemm_body<4>(As, Bs, wob, Ot, (void*)out, CCH, LL, CCH,
                 0, CL, CL, CL, bo, nullptr, xr,
                 wk & 31, (wk >> 5) & 3, wk >> 7);
}

// ---------------------------------------------------------------------------
// Flash attention v15 = v7 VERBATIM (empirical best). All 8 perturbations
// regressed (+16..+142us); declared structural floor for this structure.
// ---------------------------------------------------------------------------
#define PSTR 88

__global__ __launch_bounds__(512, 2) void flash_attn(
    const __bf16* __restrict__ QK, const __bf16* __restrict__ Vb,
    __bf16* __restrict__ Ot)
{
    __shared__ __align__(16) __bf16 Ks[16 * 64 * 32];   // [kc:16][j:64][k:32] 64 KB
    __shared__ __align__(16) __bf16 Vs[2 * 512 * 32];   // [jc:2][c:512][j:32] 64 KB
    __shared__ float  Sm[64 * 68];                      // k-half merge, 17 KB
    __shared__ __align__(16) __bf16 Ps[64 * PSTR];      // 11 KB
    __shared__ float Lp[64 * 2];                        // l partials per jh

    const int tid = threadIdx.x;
    const int l = tid & 63, w = tid >> 6;
    const int wi = w & 1, jh = (w >> 1) & 1, kh = w >> 2;
    const int g = l >> 4, c = l & 15;
    // XCD-pair batch pinning (verified r6: FETCH 139->41 MB)
    const int b = (blockIdx.x & 7) >> 1;
    const int qt = ((blockIdx.x >> 3) << 1) | (blockIdx.x & 1);
    const int i0 = qt * 64;
    const size_t bb2 = (size_t)b * LL * QSTR;   // QK batch base
    const size_t bb  = (size_t)b * CL;          // V/O batch base
    const float alpha = 0.044194173824159216f;  // 1/sqrt(512)

    int jj, cc; swz_src(l, jj, cc);
    const int slot = swz_slot(c, g);

    // Q fragments: wave owns rows [i0+wi*32,+32) (2 frags), k-half kh*256
    bf16x8 Qf[2][8];
    {
        const __bf16* Qg = QK + bb2 + (size_t)(i0 + wi*32 + c) * QSTR + kh*256 + g*8;
#pragma unroll
        for (int mi = 0; mi < 2; ++mi)
#pragma unroll
            for (int kc = 0; kc < 8; ++kc)
                Qf[mi][kc] = *(const bf16x8*)(Qg + (size_t)mi*16*QSTR + kc*32);
    }

    f32x4 Oacc[4][4];
#pragma unroll
    for (int mi = 0; mi < 4; ++mi)
#pragma unroll
        for (int ni = 0; ni < 4; ++ni) Oacc[mi][ni] = f32x4{0.f, 0.f, 0.f, 0.f};
    float l_r[4] = {0.f, 0.f, 0.f, 0.f};

    const __bf16* Kb = QK + bb2 + 512;   // K columns of fused buffer
    const __bf16* Vg = Vb + bb;

    // K staging: wave stages kc = {w, w+8}
    auto stageK = [&](int j0) {
#pragma unroll
        for (int q = 0; q < 2; ++q) {
            int kc = q * 8 + w;
#pragma unroll
            for (int p = 0; p < 4; ++p) {
                const __bf16* src = Kb + (size_t)(j0 + p*16 + jj) * QSTR + kc*32 + cc*8;
                GLOAD_LDS16(src, (char*)Ks + kc*4096 + p*1024);
            }
        }
    };
    // V staging: wave stages c-rows [w*64,+64)
    auto stageV = [&](int j0) {
#pragma unroll
        for (int jc = 0; jc < 2; ++jc)
#pragma unroll
            for (int p = 0; p < 4; ++p) {
                const __bf16* src = Vg + (size_t)(w*64 + p*16 + jj) * LL + j0 + jc*32 + cc*8;
                GLOAD_LDS16(src, (char*)Vs + jc*32768 + (w*64 + p*16)*64);
            }
    };

    // export partner frag mi=(1-kh) to Sm (v5 layout; uniform-branch static idx)
    auto expst = [&](const f32x4 (&Sx)[2]) {
        const int er0 = wi*32 + (1 - kh)*16 + g*4;
#pragma unroll
        for (int tj = 0; tj < 2; ++tj)
#pragma unroll
            for (int r = 0; r < 4; ++r)
                Sm[(er0 + r)*68 + (jh*2 + tj)*16 + c] = Sx[tj][r];
    };
    // merge + exp own rows mi=kh
    auto smx = [&](const f32x4 (&Sown)[2]) {
        const int row0 = wi*32 + kh*16 + g*4;
#pragma unroll
        for (int r = 0; r < 4; ++r) {
            float rs = 0.f;
#pragma unroll
            for (int tj = 0; tj < 2; ++tj) {
                float p = __expf((Sown[tj][r] + Sm[(row0 + r)*68 + (jh*2 + tj)*16 + c]) * alpha);
                rs += p;
                Ps[(row0 + r) * PSTR + (jh*2 + tj)*16 + c] = (__bf16)p;
            }
            l_r[r] += rs;
        }
    };

    stageK(0);
    for (int t = 0; t < 64; ++t) {
        __syncthreads();             // B1: K(t) staged; prior PV done
        stageV(t * 64);              // drains at B2

        // S partial: rows [wi*32,+32), cols [jh*32,+32), k-half kh
        f32x4 S[2][2];
#pragma unroll
        for (int mi = 0; mi < 2; ++mi)
#pragma unroll
            for (int tj = 0; tj < 2; ++tj) S[mi][tj] = f32x4{0.f,0.f,0.f,0.f};
        __builtin_amdgcn_s_setprio(1);
#pragma unroll
        for (int kc = 0; kc < 8; ++kc) {
#pragma unroll
            for (int tj = 0; tj < 2; ++tj) {
                bf16x8 kf = *(const bf16x8*)(Ks + (kh*8 + kc)*2048 + (jh*2 + tj)*512 + slot*8);
#pragma unroll
                for (int mi = 0; mi < 2; ++mi)
                    S[mi][tj] = __builtin_amdgcn_mfma_f32_16x16x32_bf16(Qf[mi][kc], kf, S[mi][tj], 0, 0, 0);
            }
        }
        __builtin_amdgcn_s_setprio(0);

        if (kh) expst(S[0]); else expst(S[1]);
        __syncthreads();             // B2: Sm visible; V(t) drained; kf reads done

        if (kh) smx(S[1]); else smx(S[0]);
        __syncthreads();             // B3: Ps visible
        if (t < 63) stageK((t + 1) * 64);   // all waves; drains at next B1 (PV cover)

        // O += P.V^T  (all 64 rows, c-slice [w*64,+64))
        __builtin_amdgcn_s_setprio(1);
#pragma unroll
        for (int jc = 0; jc < 2; ++jc) {
            bf16x8 pa[4];
#pragma unroll
            for (int mi = 0; mi < 4; ++mi)
                pa[mi] = *(const bf16x8*)(Ps + (mi*16 + c) * PSTR + jc*32 + g*8);
#pragma unroll
            for (int ni = 0; ni < 4; ++ni) {
                bf16x8 vf = *(const bf16x8*)(Vs + jc*16384 + (w*64 + ni*16)*32 + slot*8);
#pragma unroll
                for (int mi = 0; mi < 4; ++mi)
                    Oacc[mi][ni] = __builtin_amdgcn_mfma_f32_16x16x32_bf16(pa[mi], vf, Oacc[mi][ni], 0, 0, 0);
            }
        }
        __builtin_amdgcn_s_setprio(0);
    }

    // l: reduce lanes (c) then publish per-(row,jh) partial; combine in epilogue
#pragma unroll
    for (int r = 0; r < 4; ++r) {
        float tot = red_sum16(l_r[r]);
        if (c == 0) Lp[(wi*32 + kh*16 + g*4 + r)*2 + jh] = tot;
    }
    __syncthreads();
#pragma unroll
    for (int mi = 0; mi < 4; ++mi) {
#pragma unroll
        for (int r = 0; r < 4; ++r) {
            int row = mi*16 + g*4 + r;
            float inv = 1.f / (Lp[row*2] + Lp[row*2 + 1]);
#pragma unroll
            for (int ni = 0; ni < 4; ++ni) {
                int col = w*64 + ni*16 + c;
                Ot[bb + (size_t)(i0 + row) * CCH + col] = (__bf16)(Oacc[mi][ni][r] * inv);
            }
        }
    }
}

// ---------------------------------------------------------------------------
extern "C" void kernel_launch(void* const* d_in, const int* in_sizes, int n_in,
                              void* d_out, int out_size, void* d_ws, size_t ws_size,
                              hipStream_t stream) {
    const float* x   = (const float*)d_in[0];
    const float* gnw = (const float*)d_in[1];
    const float* gnb = (const float*)d_in[2];
    const float* wq  = (const float*)d_in[3];
    const float* bq  = (const float*)d_in[4];
    const float* wk  = (const float*)d_in[5];
    const float* bk  = (const float*)d_in[6];
    const float* wv  = (const float*)d_in[7];
    const float* bv  = (const float*)d_in[8];
    const float* wo  = (const float*)d_in[9];
    const float* bo  = (const float*)d_in[10];
    float* out = (float*)d_out;

    // ws (bf16): Ht | QK(2x) | Vb | Ot | Wb(4 weights) | stats  ~= 82 MiB
    __bf16* wsb = (__bf16*)d_ws;
    const size_t NCL = (size_t)NB * CL;
    __bf16* Ht  = wsb;
    __bf16* QKt = Ht + NCL;            // [NB][L][1024]
    __bf16* Vb  = QKt + 2 * NCL;
    __bf16* Ot  = Vb + NCL;
    __bf16* Wb  = Ot + NCL;            // wq|wk|wv|wo bf16, contiguous
    float* stats = (float*)(Wb + (size_t)4 * CCH * CCH);  // [128][4] partials
    __bf16* wqkb = Wb;                             // [1024][512] stacked
    __bf16* wvb  = Wb + (size_t)2 * CCH * CCH;
    __bf16* wob  = Wb + (size_t)3 * CCH * CCH;

    tobf16_4<<<dim3(256, 4), 256, 0, stream>>>(wq, wk, wv, wo, Wb);
    gn_stats<<<NB * GRP * 2, 1024, 0, stream>>>(x, stats);
    gn_norm_t<<<dim3(LL / 64, CCH / 64, NB), 256, 0, stream>>>(x, gnw, gnb, stats, Ht);

    // fused QK + V GEMMs (tail-fill), XCD-chunked mapping
    gemm_qkv<<<dim3(1536), 256, 0, stream>>>(Ht, wqkb, QKt, wvb, Vb, bq, bk, bv);

    flash_attn<<<dim3(256), 512, 0, stream>>>(QKt, Vb, Ot);

    // out[d][l] = Wo.Ot^T + bo + x  (fp32 out), XCD-chunked mapping
    gemm_out<<<dim3(512), 256, 0, stream>>>(wob, Ot, out, bo, x);
}